// Round 1
// baseline (896.899 us; speedup 1.0000x reference)
//
#include <hip/hip_runtime.h>
#include <float.h>

// Sparsemax attention: B=2, H=16, S=2048, D=64, fp32, temperature 8.
// One block = 8 q-rows of one (b,h). Phases:
//   1) scores[8][2048] = Q K^T / 8 into LDS (quad-per-k, float4 loads)
//   2) per-wave (2 rows/wave): max-reduce, collect candidates {s > max-1},
//      exact tau via Michelot on candidate list (support of sparsemax is
//      provably inside this list), sparse PV over candidates.
//      Fallback (list overflow): 40-iter bisection + dense PV (correct for
//      any input, never hit for Gaussian scores).

#define S_LEN 2048
#define DHEAD 64
#define ROWS 8
#define CAP 128

__global__ __launch_bounds__(256, 2)
void sparsemax_attn_kernel(const float* __restrict__ Q,
                           const float* __restrict__ K,
                           const float* __restrict__ V,
                           float* __restrict__ O) {
    __shared__ float s_scores[ROWS][S_LEN];   // 64 KB
    __shared__ float s_q[ROWS][DHEAD];        // 2 KB
    __shared__ float s_lv[ROWS][CAP];         // 4 KB
    __shared__ int   s_lk[ROWS][CAP];         // 4 KB
    __shared__ int   s_cnt[ROWS];

    const int t   = threadIdx.x;
    const int nrb = S_LEN / ROWS;             // 256 row-blocks per (b,h)
    const int bh  = blockIdx.x / nrb;
    const int rb  = blockIdx.x % nrb;
    const int row0 = rb * ROWS;

    const float* Qb = Q + (size_t)bh * S_LEN * DHEAD;
    const float* Kb = K + (size_t)bh * S_LEN * DHEAD;
    const float* Vb = V + (size_t)bh * S_LEN * DHEAD;
    float*       Ob = O + (size_t)bh * S_LEN * DHEAD;

    if (t < ROWS) s_cnt[t] = 0;

    // ---- load the 8 q rows into LDS (float4, coalesced) ----
    if (t < ROWS * DHEAD / 4) {
        const int r  = t >> 4;        // 16 float4 per row
        const int c4 = t & 15;
        reinterpret_cast<float4*>(&s_q[r][0])[c4] =
            reinterpret_cast<const float4*>(Qb + (size_t)(row0 + r) * DHEAD)[c4];
    }
    __syncthreads();

    // ---- phase 1: scores. 4 lanes per k (d-split 16), 64 k per 256 threads ----
    const int klocal = t >> 2;        // 0..63
    const int qd     = t & 3;         // quad lane: d-offset = qd*16
    const float4* K4 = reinterpret_cast<const float4*>(Kb);

    for (int tile = 0; tile < S_LEN / 64; ++tile) {
        const int k = tile * 64 + klocal;
        float4 kv[4];
        #pragma unroll
        for (int j = 0; j < 4; ++j) kv[j] = K4[(size_t)k * 16 + qd * 4 + j];

        #pragma unroll
        for (int r = 0; r < ROWS; ++r) {
            const float4* q4 = reinterpret_cast<const float4*>(&s_q[r][qd * 16]);
            float p = 0.f;
            #pragma unroll
            for (int j = 0; j < 4; ++j) {
                float4 qv = q4[j];
                p = fmaf(qv.x, kv[j].x, p);
                p = fmaf(qv.y, kv[j].y, p);
                p = fmaf(qv.z, kv[j].z, p);
                p = fmaf(qv.w, kv[j].w, p);
            }
            // quad reduce (lanes grouped by 4, aligned)
            p += __shfl_xor(p, 1);
            p += __shfl_xor(p, 2);
            if (qd == 0) s_scores[r][k] = p * 0.125f;   // / TEMPERATURE
        }
    }
    __syncthreads();

    // ---- phase 2: per-wave sparsemax + PV, 2 rows per wave ----
    const int wid  = t >> 6;
    const int lane = t & 63;

    for (int rr = 0; rr < 2; ++rr) {
        const int r = wid * 2 + rr;

        // row max
        float m = -FLT_MAX;
        #pragma unroll
        for (int j = 0; j < S_LEN / 64; ++j)
            m = fmaxf(m, s_scores[r][j * 64 + lane]);
        #pragma unroll
        for (int o = 32; o; o >>= 1) m = fmaxf(m, __shfl_xor(m, o));

        const float thr = m - 1.0f;   // tau* >= max-1, support is inside {s > thr}

        // collect candidates
        for (int j = 0; j < S_LEN / 64; ++j) {
            const int k = j * 64 + lane;
            const float s = s_scores[r][k];
            if (s > thr) {
                const int pos = atomicAdd(&s_cnt[r], 1);
                if (pos < CAP) { s_lv[r][pos] = s; s_lk[r][pos] = k; }
            }
        }
        const int n = s_cnt[r];       // uniform (same-wave LDS ops are ordered)

        float tau;
        if (n <= CAP) {
            // ---- Michelot on candidate list (exact, finite convergence) ----
            float cv0 = (lane < n)      ? s_lv[r][lane]      : -FLT_MAX;
            float cv1 = (lane + 64 < n) ? s_lv[r][lane + 64] : -FLT_MAX;
            tau = -FLT_MAX;
            int last = -1;
            for (int it = 0; it < CAP + 4; ++it) {
                float sm = ((cv0 > tau) ? cv0 : 0.f) + ((cv1 > tau) ? cv1 : 0.f);
                int   c  = ((cv0 > tau) ? 1 : 0)     + ((cv1 > tau) ? 1 : 0);
                #pragma unroll
                for (int o = 32; o; o >>= 1) {
                    sm += __shfl_xor(sm, o);
                    c  += __shfl_xor(c, o);
                }
                if (c == last) break;
                tau  = (sm - 1.0f) / (float)c;
                last = c;
            }
            // ---- sparse PV over candidates ----
            float acc = 0.f;
            for (int i = 0; i < n; ++i) {
                const float p = s_lv[r][i] - tau;     // broadcast reads
                if (p > 0.f)                           // uniform branch
                    acc += p * Vb[(size_t)s_lk[r][i] * DHEAD + lane];
            }
            Ob[(size_t)(row0 + r) * DHEAD + lane] = acc;
        } else {
            // ---- fallback: bisection on full row (correct for any data) ----
            float lo = m - 1.0f, hi = m;
            for (int it = 0; it < 40; ++it) {
                const float mid = 0.5f * (lo + hi);
                float sm = 0.f;
                #pragma unroll
                for (int j = 0; j < S_LEN / 64; ++j)
                    sm += fmaxf(s_scores[r][j * 64 + lane] - mid, 0.f);
                #pragma unroll
                for (int o = 32; o; o >>= 1) sm += __shfl_xor(sm, o);
                if (sm > 1.0f) lo = mid; else hi = mid;
            }
            float sm = 0.f; int c = 0;
            #pragma unroll
            for (int j = 0; j < S_LEN / 64; ++j) {
                const float s = s_scores[r][j * 64 + lane];
                if (s > lo) { sm += s; ++c; }
            }
            #pragma unroll
            for (int o = 32; o; o >>= 1) {
                sm += __shfl_xor(sm, o);
                c  += __shfl_xor(c, o);
            }
            tau = (sm - 1.0f) / (float)c;
            float acc = 0.f;
            for (int k = 0; k < S_LEN; ++k) {
                const float p = s_scores[r][k] - tau;  // broadcast read
                if (p > 0.f)                            // uniform branch
                    acc += p * Vb[(size_t)k * DHEAD + lane];
            }
            Ob[(size_t)(row0 + r) * DHEAD + lane] = acc;
        }
    }
}

extern "C" void kernel_launch(void* const* d_in, const int* in_sizes, int n_in,
                              void* d_out, int out_size, void* d_ws, size_t ws_size,
                              hipStream_t stream) {
    const float* q = (const float*)d_in[0];
    const float* k = (const float*)d_in[1];
    const float* v = (const float*)d_in[2];
    float* out = (float*)d_out;

    const int BH = in_sizes[0] / (S_LEN * DHEAD);   // 32
    const int grid = BH * (S_LEN / ROWS);           // 8192 blocks
    sparsemax_attn_kernel<<<grid, 256, 0, stream>>>(q, k, v, out);
}